// Round 3
// baseline (365.174 us; speedup 1.0000x reference)
//
#include <hip/hip_runtime.h>
#include <hip/hip_bf16.h>

#define B_  8
#define C_  256
#define C2_ 128
#define N_  4096
#define LOG2E 1.44269504088896f
#define LD_  136   // bf16 tile row stride: 272B, 16B-aligned vec8, 2-way banks (free)
#define LDF_ 132   // fp32 tile row stride: 528B, 16B-aligned vec4, 2-way banks (free)

typedef short bf16x8 __attribute__((ext_vector_type(8)));
typedef float f32x4  __attribute__((ext_vector_type(4)));

__device__ __forceinline__ float bf2f(unsigned short u) {
  union { float f; unsigned i; } v; v.i = ((unsigned)u) << 16; return v.f;
}
__device__ __forceinline__ unsigned short f2bf(float f) {
  union { float f; unsigned i; } v; v.f = f;
  unsigned r = v.i + 0x7fffu + ((v.i >> 16) & 1u);   // RNE
  return (unsigned short)(r >> 16);
}

// ---------------------------------------------------------------------------
// Kernel A: conv1 (fp32 in, split-bf16 out).
// Y[b,n,c2] = sum_c x[b,c,n]*W1[c2,c] + b1[c2], computed as 3-pass split GEMM
// (Ah*Bh + Ah*Bl + Al*Bh) so Y is fp32-accurate to ~2^-17 rel.
// Grid (32 n-tiles, 8 b). K=256 in 4 chunks of 64. Stores Yh/Yl bf16 pairs.
// ---------------------------------------------------------------------------
__global__ __launch_bounds__(256, 1)
void conv1_kernel(const float* __restrict__ x,
                  const float* __restrict__ W1,
                  const float* __restrict__ b1,
                  unsigned short* __restrict__ Yh,
                  unsigned short* __restrict__ Yl)
{
  __shared__ float          Xr[64 * LDF_];     // [c_local][n_local] fp32
  __shared__ unsigned short Ah[8 * 128 * 8];   // [c>>3][n][c&7] hi
  __shared__ unsigned short Al[8 * 128 * 8];   // lo

  const int t = threadIdx.x;
  const int w = t >> 6, lane = t & 63, quad = lane >> 4, l16 = lane & 15;
  const int nt0 = blockIdx.x, b = blockIdx.y;

  f32x4 acc[2][8];
#pragma unroll
  for (int i = 0; i < 2; i++)
#pragma unroll
    for (int j = 0; j < 8; j++) acc[i][j] = (f32x4){0.f, 0.f, 0.f, 0.f};

#pragma unroll 1
  for (int kc = 0; kc < 4; kc++) {
    // stage 64c x 128n fp32, coalesced along n
#pragma unroll
    for (int pass = 0; pass < 8; pass++) {
      int r  = (t >> 5) + pass * 8;           // c_local 0..63
      int c4 = (t & 31) * 4;                  // n_local
      float4 v = *(const float4*)(x + ((long)(b * C_ + kc * 64 + r)) * N_ + nt0 * 128 + c4);
      *(float4*)(&Xr[r * LDF_ + c4]) = v;
    }
    __syncthreads();
    // transpose + split into A-layout [c>>3][n][c&7]
#pragma unroll
    for (int pass = 0; pass < 4; pass++) {
      int n = t & 127;
      int q = (t >> 7) + pass * 2;            // 0..7
      bf16x8 vh, vl;
#pragma unroll
      for (int jj = 0; jj < 8; jj++) {
        float f = Xr[(q * 8 + jj) * LDF_ + n];
        unsigned short h = f2bf(f);
        vh[jj] = (short)h;
        vl[jj] = (short)f2bf(f - bf2f(h));
      }
      *(bf16x8*)(&Ah[(q * 128 + n) * 8]) = vh;
      *(bf16x8*)(&Al[(q * 128 + n) * 8]) = vl;
    }
    __syncthreads();
#pragma unroll
    for (int ks2 = 0; ks2 < 2; ks2++) {
      bf16x8 bh[8], bl[8];
#pragma unroll
      for (int nt = 0; nt < 8; nt++) {
        int c2 = nt * 16 + l16;
        int c  = kc * 64 + ks2 * 32 + quad * 8;
        const float* wp = W1 + c2 * C_ + c;
        float4 f0 = *(const float4*)(wp);
        float4 f1 = *(const float4*)(wp + 4);
        float fv[8] = {f0.x, f0.y, f0.z, f0.w, f1.x, f1.y, f1.z, f1.w};
#pragma unroll
        for (int jj = 0; jj < 8; jj++) {
          unsigned short h = f2bf(fv[jj]);
          bh[nt][jj] = (short)h;
          bl[nt][jj] = (short)f2bf(fv[jj] - bf2f(h));
        }
      }
#pragma unroll
      for (int mt = 0; mt < 2; mt++) {
        int n = w * 32 + mt * 16 + l16;
        int q = ks2 * 4 + quad;
        bf16x8 ah = *(const bf16x8*)(&Ah[(q * 128 + n) * 8]);
        bf16x8 al = *(const bf16x8*)(&Al[(q * 128 + n) * 8]);
#pragma unroll
        for (int nt = 0; nt < 8; nt++) {
          acc[mt][nt] = __builtin_amdgcn_mfma_f32_16x16x32_bf16(ah, bh[nt], acc[mt][nt], 0, 0, 0);
          acc[mt][nt] = __builtin_amdgcn_mfma_f32_16x16x32_bf16(ah, bl[nt], acc[mt][nt], 0, 0, 0);
          acc[mt][nt] = __builtin_amdgcn_mfma_f32_16x16x32_bf16(al, bh[nt], acc[mt][nt], 0, 0, 0);
        }
      }
    }
    __syncthreads();
  }
  // epilogue: +b1 (fp32), split-store
#pragma unroll
  for (int nt = 0; nt < 8; nt++) {
    int c2 = nt * 16 + l16;
    float bv = b1[c2];
#pragma unroll
    for (int mt = 0; mt < 2; mt++)
#pragma unroll
      for (int rg = 0; rg < 4; rg++) {
        int row = w * 32 + mt * 16 + quad * 4 + rg;
        long o = ((long)b * N_ + nt0 * 128 + row) * C2_ + c2;
        float yv = acc[mt][nt][rg] + bv;
        unsigned short h = f2bf(yv);
        Yh[o] = h;
        Yl[o] = f2bf(yv - bf2f(h));
      }
  }
}

// ---------------------------------------------------------------------------
// Kernel B: flash attention, unscaled, Q=K=V=Y (split hi/lo). Grid (32,8).
// S = Qh*Kh + Qh*Kl + Ql*Kh (3-pass split QK^T); PV uses hi only.
// LDS: Kh 34K + Kl 34K + Ps 34K + Vs 32K = 134 KB (gfx950 allows 160).
// ---------------------------------------------------------------------------
__global__ __launch_bounds__(256, 1)
void attn_kernel(const unsigned short* __restrict__ Yh,
                 const unsigned short* __restrict__ Yl,
                 unsigned short* __restrict__ O)
{
  __shared__ unsigned short Kh[128 * LD_];
  __shared__ unsigned short Kl[128 * LD_];
  __shared__ unsigned short Ps[128 * LD_];     // Q-stage, then P tile
  __shared__ unsigned short Vs[16 * 128 * 8];  // [kk>>3][d][kk&7] (hi)

  const int t = threadIdx.x;
  const int w = t >> 6, lane = t & 63, quad = lane >> 4, l16 = lane & 15;
  const int qt = blockIdx.x, b = blockIdx.y;
  const unsigned short* Yhb = Yh + (long)b * N_ * C2_;
  const unsigned short* Ylb = Yl + (long)b * N_ * C2_;
  unsigned short* Ob = O + (long)b * N_ * C2_;

  bf16x8 qh[2][4], ql[2][4];
  // stage Q_hi, grab frags; then Q_lo
#pragma unroll 1
  for (int piece = 0; piece < 2; piece++) {
    const unsigned short* src = piece ? Ylb : Yhb;
#pragma unroll
    for (int pass = 0; pass < 8; pass++) {
      int r = (t >> 4) + pass * 16, c8 = (t & 15) * 8;
      *(bf16x8*)(&Ps[r * LD_ + c8]) =
          *(const bf16x8*)(src + (long)(qt * 128 + r) * C2_ + c8);
    }
    __syncthreads();
#pragma unroll
    for (int mt = 0; mt < 2; mt++) {
      int r = w * 32 + mt * 16 + l16;
#pragma unroll
      for (int ks = 0; ks < 4; ks++) {
        bf16x8 v = *(const bf16x8*)(&Ps[r * LD_ + ks * 32 + quad * 8]);
        if (piece) ql[mt][ks] = v; else qh[mt][ks] = v;
      }
    }
    __syncthreads();
  }

  f32x4 Oa[2][8];
#pragma unroll
  for (int i = 0; i < 2; i++)
#pragma unroll
    for (int j = 0; j < 8; j++) Oa[i][j] = (f32x4){0.f, 0.f, 0.f, 0.f};
  float mrun[2][4], lrun[2][4];
#pragma unroll
  for (int i = 0; i < 2; i++)
#pragma unroll
    for (int j = 0; j < 4; j++) { mrun[i][j] = -1e30f; lrun[i][j] = 0.f; }

#pragma unroll 1
  for (int kt = 0; kt < 32; kt++) {
    // stage K hi+lo tiles
#pragma unroll
    for (int pass = 0; pass < 8; pass++) {
      int r = (t >> 4) + pass * 16, c8 = (t & 15) * 8;
      long src = (long)(kt * 128 + r) * C2_ + c8;
      *(bf16x8*)(&Kh[r * LD_ + c8]) = *(const bf16x8*)(Yhb + src);
      *(bf16x8*)(&Kl[r * LD_ + c8]) = *(const bf16x8*)(Ylb + src);
    }
    __syncthreads();   // B1
    // repack V(=K hi) into k-inner-8
#pragma unroll
    for (int pass = 0; pass < 8; pass++) {
      int d = t & 127;
      int q = (t >> 7) + pass * 2;
      bf16x8 vv;
#pragma unroll
      for (int jj = 0; jj < 8; jj++)
        vv[jj] = (short)Kh[(q * 8 + jj) * LD_ + d];
      *(bf16x8*)(&Vs[(q * 128 + d) * 8]) = vv;
    }
    // S = Qh Kh^T + Qh Kl^T + Ql Kh^T
    f32x4 S[2][8];
#pragma unroll
    for (int i = 0; i < 2; i++)
#pragma unroll
      for (int j = 0; j < 8; j++) S[i][j] = (f32x4){0.f, 0.f, 0.f, 0.f};
#pragma unroll
    for (int ks = 0; ks < 4; ks++) {
      bf16x8 bh[8], bl[8];
#pragma unroll
      for (int nt = 0; nt < 8; nt++) {
        int r = nt * 16 + l16, k = ks * 32 + quad * 8;
        bh[nt] = *(const bf16x8*)(&Kh[r * LD_ + k]);
        bl[nt] = *(const bf16x8*)(&Kl[r * LD_ + k]);
      }
#pragma unroll
      for (int mt = 0; mt < 2; mt++)
#pragma unroll
        for (int nt = 0; nt < 8; nt++) {
          S[mt][nt] = __builtin_amdgcn_mfma_f32_16x16x32_bf16(qh[mt][ks], bh[nt], S[mt][nt], 0, 0, 0);
          S[mt][nt] = __builtin_amdgcn_mfma_f32_16x16x32_bf16(qh[mt][ks], bl[nt], S[mt][nt], 0, 0, 0);
          S[mt][nt] = __builtin_amdgcn_mfma_f32_16x16x32_bf16(ql[mt][ks], bh[nt], S[mt][nt], 0, 0, 0);
        }
    }
    __syncthreads();   // B2: Vs writes + K reads done
    // online softmax (rows = quad*4+rg; 16-lane butterfly over l16)
#pragma unroll
    for (int mt = 0; mt < 2; mt++)
#pragma unroll
      for (int rg = 0; rg < 4; rg++) {
        float smax = S[mt][0][rg];
#pragma unroll
        for (int nt = 1; nt < 8; nt++) smax = fmaxf(smax, S[mt][nt][rg]);
#pragma unroll
        for (int off = 8; off >= 1; off >>= 1) smax = fmaxf(smax, __shfl_xor(smax, off));
        float newm = fmaxf(mrun[mt][rg], smax);
        float alpha = exp2f(fminf((mrun[mt][rg] - newm) * LOG2E, 0.f));
        mrun[mt][rg] = newm;
        float ps = 0.f;
#pragma unroll
        for (int nt = 0; nt < 8; nt++) {
          float p = exp2f(fminf((S[mt][nt][rg] - newm) * LOG2E, 0.f));
          S[mt][nt][rg] = p;
          ps += p;
        }
#pragma unroll
        for (int off = 8; off >= 1; off >>= 1) ps += __shfl_xor(ps, off);
        lrun[mt][rg] = lrun[mt][rg] * alpha + ps;
#pragma unroll
        for (int dt = 0; dt < 8; dt++) Oa[mt][dt][rg] *= alpha;
      }
    // write P (bf16)
#pragma unroll
    for (int mt = 0; mt < 2; mt++)
#pragma unroll
      for (int nt = 0; nt < 8; nt++)
#pragma unroll
        for (int rg = 0; rg < 4; rg++) {
          int r = w * 32 + mt * 16 + quad * 4 + rg;
          Ps[r * LD_ + nt * 16 + l16] = f2bf(S[mt][nt][rg]);
        }
    __syncthreads();   // B3: P complete
    // O += P V
#pragma unroll
    for (int ks = 0; ks < 4; ks++) {
      bf16x8 vb[8];
#pragma unroll
      for (int dt = 0; dt < 8; dt++)
        vb[dt] = *(const bf16x8*)(&Vs[((ks * 4 + quad) * 128 + dt * 16 + l16) * 8]);
      bf16x8 pa[2];
#pragma unroll
      for (int mt = 0; mt < 2; mt++) {
        int r = w * 32 + mt * 16 + l16;
        pa[mt] = *(const bf16x8*)(&Ps[r * LD_ + ks * 32 + quad * 8]);
      }
#pragma unroll
      for (int mt = 0; mt < 2; mt++)
#pragma unroll
        for (int dt = 0; dt < 8; dt++)
          Oa[mt][dt] = __builtin_amdgcn_mfma_f32_16x16x32_bf16(pa[mt], vb[dt], Oa[mt][dt], 0, 0, 0);
    }
    __syncthreads();   // B4
  }
#pragma unroll
  for (int mt = 0; mt < 2; mt++)
#pragma unroll
    for (int rg = 0; rg < 4; rg++) {
      float inv = 1.0f / fmaxf(lrun[mt][rg], 1e-20f);
      int r = w * 32 + mt * 16 + quad * 4 + rg;
#pragma unroll
      for (int dt = 0; dt < 8; dt++)
        Ob[(long)(qt * 128 + r) * C2_ + dt * 16 + l16] = f2bf(Oa[mt][dt][rg] * inv);
    }
}

// ---------------------------------------------------------------------------
// Kernel C: conv2 + scale + residual (fp32 in/out, O bf16). torch .view ==
// reinterpret O[b] as [128][4096]. out = (W2·view + b2)*scale + x, W2 split.
// ---------------------------------------------------------------------------
__global__ __launch_bounds__(256, 1)
void conv2_kernel(const unsigned short* __restrict__ O,
                  const float* __restrict__ W2,
                  const float* __restrict__ b2,
                  const float* __restrict__ scale,
                  const float* __restrict__ x,
                  float* __restrict__ out)
{
  __shared__ unsigned short Or[128 * LD_];
  __shared__ unsigned short Bsw[16 * 128 * 8];

  const int t = threadIdx.x;
  const int w = t >> 6, lane = t & 63, quad = lane >> 4, l16 = lane & 15;
  const int pt = blockIdx.x, b = blockIdx.y;
  const unsigned short* Obv = O + (long)b * N_ * C2_;  // view [128][4096]

#pragma unroll
  for (int pass = 0; pass < 8; pass++) {
    int r = (t >> 4) + pass * 16, c8 = (t & 15) * 8;
    *(bf16x8*)(&Or[r * LD_ + c8]) =
        *(const bf16x8*)(Obv + (long)r * N_ + pt * 128 + c8);
  }
  __syncthreads();
#pragma unroll
  for (int pass = 0; pass < 8; pass++) {
    int p = t & 127;
    int q = (t >> 7) + pass * 2;
    bf16x8 vv;
#pragma unroll
    for (int jj = 0; jj < 8; jj++)
      vv[jj] = (short)Or[(q * 8 + jj) * LD_ + p];
    *(bf16x8*)(&Bsw[(q * 128 + p) * 8]) = vv;
  }
  __syncthreads();

  f32x4 acc[4][8];
#pragma unroll
  for (int i = 0; i < 4; i++)
#pragma unroll
    for (int j = 0; j < 8; j++) acc[i][j] = (f32x4){0.f, 0.f, 0.f, 0.f};

#pragma unroll
  for (int ks = 0; ks < 4; ks++) {
    bf16x8 bfr[8];
#pragma unroll
    for (int nt = 0; nt < 8; nt++)
      bfr[nt] = *(const bf16x8*)(&Bsw[((ks * 4 + quad) * 128 + nt * 16 + l16) * 8]);
#pragma unroll
    for (int mt = 0; mt < 4; mt++) {
      int o = w * 64 + mt * 16 + l16;
      const float* wp = W2 + o * C2_ + ks * 32 + quad * 8;
      float4 f0 = *(const float4*)(wp);
      float4 f1 = *(const float4*)(wp + 4);
      float fv[8] = {f0.x, f0.y, f0.z, f0.w, f1.x, f1.y, f1.z, f1.w};
      bf16x8 ah, al;
#pragma unroll
      for (int jj = 0; jj < 8; jj++) {
        unsigned short h = f2bf(fv[jj]);
        ah[jj] = (short)h;
        al[jj] = (short)f2bf(fv[jj] - bf2f(h));
      }
#pragma unroll
      for (int nt = 0; nt < 8; nt++) {
        acc[mt][nt] = __builtin_amdgcn_mfma_f32_16x16x32_bf16(ah, bfr[nt], acc[mt][nt], 0, 0, 0);
        acc[mt][nt] = __builtin_amdgcn_mfma_f32_16x16x32_bf16(al, bfr[nt], acc[mt][nt], 0, 0, 0);
      }
    }
  }
#pragma unroll
  for (int mt = 0; mt < 4; mt++)
#pragma unroll
    for (int rg = 0; rg < 4; rg++) {
      int o = w * 64 + mt * 16 + quad * 4 + rg;
      float so = scale[o], bo = b2[o];
#pragma unroll
      for (int nt = 0; nt < 8; nt++) {
        int p = pt * 128 + nt * 16 + l16;
        long xo = ((long)b * C_ + o) * N_ + p;
        out[xo] = (acc[mt][nt][rg] + bo) * so + x[xo];
      }
    }
}

extern "C" void kernel_launch(void* const* d_in, const int* in_sizes, int n_in,
                              void* d_out, int out_size, void* d_ws, size_t ws_size,
                              hipStream_t stream) {
  const float* x     = (const float*)d_in[0];
  const float* W1    = (const float*)d_in[1];
  const float* b1    = (const float*)d_in[2];
  const float* W2    = (const float*)d_in[3];
  const float* b2    = (const float*)d_in[4];
  const float* scale = (const float*)d_in[5];
  float* outp = (float*)d_out;

  unsigned short* Yh = (unsigned short*)d_ws;            // [8][4096][128] bf16 hi (8 MiB)
  unsigned short* Yl = Yh + (size_t)B_ * N_ * C2_;       // lo (8 MiB)
  unsigned short* O  = Yl + (size_t)B_ * N_ * C2_;       // attn out hi (8 MiB)

  dim3 grid(32, 8), blk(256);
  conv1_kernel<<<grid, blk, 0, stream>>>(x, W1, b1, Yh, Yl);
  attn_kernel <<<grid, blk, 0, stream>>>(Yh, Yl, O);
  conv2_kernel<<<grid, blk, 0, stream>>>(O, W2, b2, scale, x, outp);
}